// Round 1
// baseline (462.727 us; speedup 1.0000x reference)
//
#include <hip/hip_runtime.h>
#include <math.h>

#define N_RES 8192
#define N_IN  256
#define BATCH 16

// ---------------------------------------------------------------------------
// init: z_acc[r*16+b] = bias[r];  state_T[r*16+b] = state[b*N_RES+r];
//       x_T[c*16+b]   = x[b*N_IN+c]
// ---------------------------------------------------------------------------
__global__ void init_kernel(const float* __restrict__ state,
                            const float* __restrict__ x,
                            const float* __restrict__ bias,
                            float* __restrict__ z_acc,
                            float* __restrict__ state_T,
                            float* __restrict__ x_T) {
    int i = blockIdx.x * blockDim.x + threadIdx.x;
    if (i < N_RES * BATCH) {
        int r = i >> 4;   // 0..8191
        int b = i & 15;
        state_T[i] = state[b * N_RES + r];
        z_acc[i]   = bias[r];
    }
    if (i < N_IN * BATCH) {
        int c = i >> 4;
        int b = i & 15;
        x_T[i] = x[b * N_IN + c];
    }
}

// ---------------------------------------------------------------------------
// scatter: each 16-lane group owns one nnz; lane b handles batch element b.
// 16 atomics per nnz land in ONE 64B cacheline -> coalesced atomic transaction.
// ---------------------------------------------------------------------------
__global__ void scatter_kernel(const float* __restrict__ vals,
                               const int* __restrict__ rows,
                               const int* __restrict__ cols,
                               const float* __restrict__ src_T,  // [n_src][16]
                               float* __restrict__ z_acc,        // [N_RES][16]
                               int nnz) {
    int tid = blockIdx.x * blockDim.x + threadIdx.x;
    int g   = tid >> 4;        // nnz group id
    int b   = tid & 15;        // batch lane
    int ngroups = (gridDim.x * blockDim.x) >> 4;
    for (int k = g; k < nnz; k += ngroups) {
        float v = vals[k];     // 16 lanes same address -> broadcast
        int   r = rows[k];
        int   c = cols[k];
        float s = src_T[(c << 4) + b];   // contiguous 64B across the group
        unsafeAtomicAdd(&z_acc[(r << 4) + b], v * s);
    }
}

// ---------------------------------------------------------------------------
// finish: out[b*N_RES + r] = erf(z_acc[r*16 + b])   (A_LEAK == 1.0)
// ---------------------------------------------------------------------------
__global__ void finish_kernel(const float* __restrict__ z_acc,
                              float* __restrict__ out) {
    int i = blockIdx.x * blockDim.x + threadIdx.x;  // i = b*N_RES + r
    if (i < N_RES * BATCH) {
        int b = i >> 13;
        int r = i & (N_RES - 1);
        out[i] = erff(z_acc[(r << 4) + b]);
    }
}

extern "C" void kernel_launch(void* const* d_in, const int* in_sizes, int n_in,
                              void* d_out, int out_size, void* d_ws, size_t ws_size,
                              hipStream_t stream) {
    const float* state    = (const float*)d_in[0];
    const float* x        = (const float*)d_in[1];
    const float* res_vals = (const float*)d_in[2];
    const int*   res_rows = (const int*)  d_in[3];
    const int*   res_cols = (const int*)  d_in[4];
    const float* res_bias = (const float*)d_in[5];
    const float* in_vals  = (const float*)d_in[6];
    const int*   in_rows  = (const int*)  d_in[7];
    const int*   in_cols  = (const int*)  d_in[8];
    float* out = (float*)d_out;

    float* ws      = (float*)d_ws;
    float* z_acc   = ws;                       // N_RES*16 floats (512 KB)
    float* state_T = z_acc + N_RES * BATCH;    // N_RES*16 floats (512 KB)
    float* x_T     = state_T + N_RES * BATCH;  // N_IN*16  floats (16 KB)

    int nnz_res = in_sizes[2];
    int nnz_in  = in_sizes[6];

    init_kernel<<<(N_RES * BATCH + 255) / 256, 256, 0, stream>>>(
        state, x, res_bias, z_acc, state_T, x_T);

    // 2048 blocks * 256 thr = 524288 threads = 32768 nnz-groups (saturates 256 CUs)
    scatter_kernel<<<2048, 256, 0, stream>>>(
        res_vals, res_rows, res_cols, state_T, z_acc, nnz_res);

    scatter_kernel<<<512, 256, 0, stream>>>(
        in_vals, in_rows, in_cols, x_T, z_acc, nnz_in);

    finish_kernel<<<(N_RES * BATCH + 255) / 256, 256, 0, stream>>>(z_acc, out);
}